// Round 1
// baseline (6250.476 us; speedup 1.0000x reference)
//
#include <hip/hip_runtime.h>

#define B_ 64
#define S_ 512
#define D_ 512
#define H_ 1024

typedef __attribute__((ext_vector_type(8))) short bf16x8;
typedef __attribute__((ext_vector_type(4))) float f32x4;
typedef unsigned short u16;
typedef unsigned int u32;

#define MFMA(a, b, c) __builtin_amdgcn_mfma_f32_16x16x32_bf16(a, b, c, 0, 0, 0)

__device__ __forceinline__ u16 f2bf(float f) {
    u32 u = __float_as_uint(f);
    u += 0x7fffu + ((u >> 16) & 1u);
    return (u16)(u >> 16);
}
__device__ __forceinline__ float sigm(float x) { return 1.0f / (1.0f + __expf(-x)); }
__device__ __forceinline__ float tanh_f(float x) { return 1.0f - 2.0f / (__expf(2.0f * x) + 1.0f); }

__device__ __forceinline__ bf16x8 cvt8(const float* p) {
    float4 f0 = ((const float4*)p)[0];
    float4 f1 = ((const float4*)p)[1];
    bf16x8 v;
    v[0] = (short)f2bf(f0.x); v[1] = (short)f2bf(f0.y);
    v[2] = (short)f2bf(f0.z); v[3] = (short)f2bf(f0.w);
    v[4] = (short)f2bf(f1.x); v[5] = (short)f2bf(f1.y);
    v[6] = (short)f2bf(f1.z); v[7] = (short)f2bf(f1.w);
    return v;
}

// ---- LLC-direct access helpers: sc0 sc1 = bypass L1+L2, served by Infinity Cache ----
__device__ __forceinline__ void llc_ld(bf16x8& d, const u16* p) {
    asm volatile("global_load_dwordx4 %0, %1, off sc0 sc1" : "=v"(d) : "v"(p));
}
__device__ __forceinline__ void vm0() {
    asm volatile("s_waitcnt vmcnt(0)" ::: "memory");
}
__device__ __forceinline__ void vmw16() {
    asm volatile("s_waitcnt vmcnt(16)" ::: "memory");
}
__device__ __forceinline__ void fence_frag(bf16x8& d) {
    asm volatile("" : "+v"(d));
}
__device__ __forceinline__ void llc_st16(u16* p, u16 v) {
    u32 vv = v;
    asm volatile("global_store_short %0, %1, off sc0 sc1" :: "v"(p), "v"(vv) : "memory");
}
__device__ __forceinline__ void llc_st32(int* p, int v) {
    asm volatile("global_store_dword %0, %1, off sc0 sc1" :: "v"(p), "v"(v) : "memory");
}
// two flag loads, one drain (poll primitive)
__device__ __forceinline__ void llc_ld2(int& a, int& b, const int* p0, const int* p1) {
    asm volatile("global_load_dword %0, %2, off sc0 sc1\n"
                 "global_load_dword %1, %3, off sc0 sc1\n"
                 "s_waitcnt vmcnt(0)"
                 : "=&v"(a), "=&v"(b) : "v"(p0), "v"(p1) : "memory");
}

// ---------------- prep: fp32 weights -> bf16 concatenated [Wih | Whh], K-contiguous ----
__global__ void prep_w(const float* __restrict__ Wih, const float* __restrict__ Whh,
                       u16* __restrict__ Wc, int Kx, int Kw, int total8) {
    int idx = blockIdx.x * 256 + threadIdx.x;
    if (idx >= total8) return;
    int kc8 = Kw >> 3;
    int n = idx / kc8;
    int kc = (idx - n * kc8) << 3;
    const float* src = (kc < Kx) ? (Wih + (size_t)n * Kx + kc)
                                 : (Whh + (size_t)n * (Kw - Kx) + (kc - Kx));
    *(bf16x8*)(Wc + (size_t)n * Kw + kc) = cvt8(src);
}

// ---------------- prep: biases + h-state init + flag zero ----------------
__global__ void prep_misc2(const float* __restrict__ h0in,
                           const float* __restrict__ bih0, const float* __restrict__ bhh0,
                           const float* __restrict__ bih1, const float* __restrict__ bhh1,
                           float* __restrict__ bias0, float* __restrict__ bias1,
                           u16* __restrict__ h0a, u16* __restrict__ h0b,
                           u16* __restrict__ h1a, u16* __restrict__ h1b,
                           int* __restrict__ bar) {
    int idx = blockIdx.x * 256 + threadIdx.x;
    if (idx < 8192) bar[idx] = 0;   // 256 flags x 32-int (128B) stride
    if (idx < 4096) { bias0[idx] = bih0[idx] + bhh0[idx]; return; }
    if (idx < 8192) { int i = idx - 4096; bias1[i] = bih1[i] + bhh1[i]; return; }
    int r = idx - 8192;
    if (r >= 2 * B_ * H_) return;
    int l = r >> 16;
    int rr = r & 65535;
    u16 hb = f2bf(h0in[r]);
    if (l == 0) { h0a[rr] = hb; h0b[rr] = hb; }
    else        { h1a[rr] = hb; h1b[rr] = hb; }
}

// ---------------- persistent LSTM kernel ----------------------------------------------
// 256 blocks (1/CU) x 512 threads (8 waves). Block bk: col-group cgp=bk>>1, row-half
// mh=bk&1. All cross-block deps are within the 128 same-mh peers (rows mh*32..+31).
// Sync: per-block flag (own 128B line) = #completed iterations, posted by tid0 via
// write-through sc0sc1 store AFTER per-wave vmcnt(0) drain + __syncthreads (so all
// waves' h-stores are at LLC and all buffer reads have sampled -> WAR/RAW safe with
// 2-deep buffers). Wait: each wave autonomously polls all 128 peer flags (2/lane,
// one LLC round per iter) -- no atomic RMW serialization, no single-thread detection,
// no cross-mh coupling. Spins bounded -> no hang possible.
__global__ __launch_bounds__(512, 2) void lstm_persist(
    const float* __restrict__ x,
    const u16* __restrict__ W0c, const u16* __restrict__ W1c,
    const float* __restrict__ bias0, const float* __restrict__ bias1,
    const float* __restrict__ c0in,
    u16* __restrict__ h0a, u16* __restrict__ h0b,
    u16* __restrict__ h1a, u16* __restrict__ h1b,
    float* __restrict__ h1f,
    int* __restrict__ bar) {
    const int bk = blockIdx.x;
    const int cgp = bk >> 1;
    const int mh = bk & 1;
    const int tid = threadIdx.x;
    const int w = tid >> 6;
    const int lane = tid & 63;
    const int quad = lane >> 4;
    const int l16 = lane & 15;

    int gc[2];
    #pragma unroll
    for (int n = 0; n < 2; ++n) {
        int c = n * 16 + l16;
        gc[n] = (c >> 3) * 1024 + cgp * 8 + (c & 7);
    }

    // --- persistent weight fragments (loaded once, live in registers) ---
    bf16x8 w0x[2][2], w0h[2][4];
    bf16x8 w1f[2][8];
    #pragma unroll
    for (int n = 0; n < 2; ++n) {
        #pragma unroll
        for (int kf = 0; kf < 2; ++kf)
            w0x[n][kf] = *(const bf16x8*)(W0c + (size_t)gc[n] * 1536 + w * 64 + kf * 32 + quad * 8);
        #pragma unroll
        for (int kf = 0; kf < 4; ++kf)
            w0h[n][kf] = *(const bf16x8*)(W0c + (size_t)gc[n] * 1536 + 512 + w * 128 + kf * 32 + quad * 8);
        #pragma unroll
        for (int kf = 0; kf < 8; ++kf)
            w1f[n][kf] = *(const bf16x8*)(W1c + (size_t)gc[n] * 2048 + w * 256 + kf * 32 + quad * 8);
    }

    // double-buffered partials: layer-1 MFMA (partB) overlaps layer-0 reduce (partA).
    // layout per wave: [b 0..31][j*4+gate] stride 36 -> reduce reads are ds_read_b128.
    __shared__ __align__(16) float partA[8 * 32 * 36];
    __shared__ __align__(16) float partB[8 * 32 * 36];
    __shared__ float c0l[256], c1l[256];
    __shared__ __align__(16) float b0l[32], b1l[32];

    if (tid < 32) {
        int gg = tid >> 3, j = tid & 7;
        b0l[j * 4 + gg] = bias0[gg * 1024 + cgp * 8 + j];
        b1l[j * 4 + gg] = bias1[gg * 1024 + cgp * 8 + j];
    }
    if (tid < 256) {
        int b = tid >> 3, j = tid & 7;
        int gi = (mh * 32 + b) * 1024 + cgp * 8 + j;
        c0l[tid] = c0in[gi];
        c1l[tid] = c0in[65536 + gi];
    }
    __syncthreads();

    const int brow0 = mh * 32 + l16;
    const int brow1 = brow0 + 16;

    // peer flag addresses: peers bk' = 2*c + mh, c = lane and lane+64
    const int* q0 = bar + (2 * lane + mh) * 32;
    const int* q1 = bar + (2 * (lane + 64) + mh) * 32;
    const int co0 = (l16 & 7) * 4 + (l16 >> 3);
    const int co1 = co0 + 2;

    // x-part accumulators (plain cached loads; L2 stays warm)
    f32x4 xacc[2][2];
    #define XPART(t)                                                                 \
        {                                                                            \
            xacc[0][0] = (f32x4){0.f,0.f,0.f,0.f}; xacc[0][1] = (f32x4){0.f,0.f,0.f,0.f}; \
            xacc[1][0] = (f32x4){0.f,0.f,0.f,0.f}; xacc[1][1] = (f32x4){0.f,0.f,0.f,0.f}; \
            _Pragma("unroll")                                                        \
            for (int kf = 0; kf < 2; ++kf) {                                         \
                int k = w * 64 + kf * 32 + quad * 8;                                 \
                bf16x8 a0 = cvt8(x + (size_t)brow0 * 262144 + (t) * 512 + k);        \
                bf16x8 a1 = cvt8(x + (size_t)brow1 * 262144 + (t) * 512 + k);        \
                xacc[0][0] = MFMA(a0, w0x[0][kf], xacc[0][0]);                       \
                xacc[0][1] = MFMA(a0, w0x[1][kf], xacc[0][1]);                       \
                xacc[1][0] = MFMA(a1, w0x[0][kf], xacc[1][0]);                       \
                xacc[1][1] = MFMA(a1, w0x[1][kf], xacc[1][1]);                       \
            }                                                                        \
        }

    XPART(0);

    for (int p = 0; p <= S_; ++p) {
        const int rd = p & 1;
        const u16* h0r = rd ? h0b : h0a;
        u16*       h0w_ = rd ? h0a : h0b;
        const u16* h1r = rd ? h1b : h1a;
        u16*       h1w_ = rd ? h1a : h1b;

        // ---- wave-autonomous wait: all 128 same-mh peers completed iteration p-1 ----
        if (p > 0) {
            int f0, f1;
            for (int it = 0; it < 40000; ++it) {
                llc_ld2(f0, f1, q0, q1);
                if (__all((f0 >= p) && (f1 >= p))) break;
            }
        }

        // ---- issue stage-A loads, then stage-B loads, then counted wait on A only ----
        bf16x8 a0[4], a1[4], pb0[8], pb1[8];
        if (p < S_) {
            #pragma unroll
            for (int kf = 0; kf < 4; ++kf) {
                int ko = w * 128 + kf * 32 + quad * 8;
                llc_ld(a0[kf], h0r + brow0 * 1024 + ko);
                llc_ld(a1[kf], h0r + brow1 * 1024 + ko);
            }
        }
        if (p >= 1) {
            #pragma unroll
            for (int kf = 0; kf < 8; ++kf) {
                int k = w * 256 + kf * 32;
                const u16* src = (k < 1024) ? h0r : h1r;
                int ko = (k & 1023) + quad * 8;
                llc_ld(pb0[kf], src + brow0 * 1024 + ko);
                llc_ld(pb1[kf], src + brow1 * 1024 + ko);
            }
        }

        // ---------- stage A: layer 0, step p (h-part; x-part precomputed) ----------
        if (p < S_) {
            if (p >= 1) vmw16(); else vm0();   // drain only the 8 a-loads; pb stays in flight
            #pragma unroll
            for (int kf = 0; kf < 4; ++kf) { fence_frag(a0[kf]); fence_frag(a1[kf]); }
            f32x4 acc00 = xacc[0][0], acc01 = xacc[0][1];
            f32x4 acc10 = xacc[1][0], acc11 = xacc[1][1];
            #pragma unroll
            for (int kf = 0; kf < 4; ++kf) {
                acc00 = MFMA(a0[kf], w0h[0][kf], acc00);
                acc01 = MFMA(a0[kf], w0h[1][kf], acc01);
                acc10 = MFMA(a1[kf], w0h[0][kf], acc10);
                acc11 = MFMA(a1[kf], w0h[1][kf], acc11);
            }
            #pragma unroll
            for (int r = 0; r < 4; ++r) {
                int b0 = quad * 4 + r, b1 = b0 + 16;
                partA[w * 1152 + b0 * 36 + co0] = acc00[r];
                partA[w * 1152 + b0 * 36 + co1] = acc01[r];
                partA[w * 1152 + b1 * 36 + co0] = acc10[r];
                partA[w * 1152 + b1 * 36 + co1] = acc11[r];
            }
        }
        __syncthreads();

        // stage-B operands ready (issued at top; latency hidden under stage A)
        if (p >= 1) {
            vm0();
            #pragma unroll
            for (int kf = 0; kf < 8; ++kf) { fence_frag(pb0[kf]); fence_frag(pb1[kf]); }
        }

        // ---- layer-0 reduce (waves 0-3) overlaps layer-1 MFMA (waves 4-7) ----
        if (p < S_ && tid < 256) {
            int b = tid >> 3, j = tid & 7;
            f32x4 s = *(const f32x4*)&b0l[j * 4];
            #pragma unroll
            for (int w8 = 0; w8 < 8; ++w8)
                s += *(const f32x4*)&partA[w8 * 1152 + b * 36 + j * 4];
            float c = c0l[tid];
            float cn = sigm(s[1]) * c + sigm(s[0]) * tanh_f(s[2]);
            float hn = sigm(s[3]) * tanh_f(cn);
            c0l[tid] = cn;
            llc_st16(h0w_ + (mh * 32 + b) * 1024 + cgp * 8 + j, f2bf(hn));
        }

        // ---------- stage B: layer 1, step p-1 ----------
        if (p >= 1) {
            f32x4 acc00 = {0.f,0.f,0.f,0.f}, acc01 = {0.f,0.f,0.f,0.f};
            f32x4 acc10 = {0.f,0.f,0.f,0.f}, acc11 = {0.f,0.f,0.f,0.f};
            #pragma unroll
            for (int kf = 0; kf < 8; ++kf) {
                acc00 = MFMA(pb0[kf], w1f[0][kf], acc00);
                acc01 = MFMA(pb0[kf], w1f[1][kf], acc01);
                acc10 = MFMA(pb1[kf], w1f[0][kf], acc10);
                acc11 = MFMA(pb1[kf], w1f[1][kf], acc11);
            }
            #pragma unroll
            for (int r = 0; r < 4; ++r) {
                int b0 = quad * 4 + r, b1 = b0 + 16;
                partB[w * 1152 + b0 * 36 + co0] = acc00[r];
                partB[w * 1152 + b0 * 36 + co1] = acc01[r];
                partB[w * 1152 + b1 * 36 + co0] = acc10[r];
                partB[w * 1152 + b1 * 36 + co1] = acc11[r];
            }
        }
        __syncthreads();
        if (p >= 1 && tid < 256) {
            int b = tid >> 3, j = tid & 7;
            f32x4 s = *(const f32x4*)&b1l[j * 4];
            #pragma unroll
            for (int w8 = 0; w8 < 8; ++w8)
                s += *(const f32x4*)&partB[w8 * 1152 + b * 36 + j * 4];
            float c = c1l[tid];
            float cn = sigm(s[1]) * c + sigm(s[0]) * tanh_f(s[2]);
            float hn = sigm(s[3]) * tanh_f(cn);
            c1l[tid] = cn;
            int gi = (mh * 32 + b) * 1024 + cgp * 8 + j;
            llc_st16(h1w_ + gi, f2bf(hn));
            if (p == S_) h1f[gi] = hn;
        }

        // ---- post own flag (all waves drained: h at LLC, all buffer reads sampled),
        //      then prefetch next x-part (overlaps next wait) ----
        if (p < S_) {
            vm0();
            __syncthreads();
            if (tid == 0) llc_st32(bar + bk * 32, p + 1);
            if (p + 1 < S_) XPART(p + 1);
        }
    }
}

// ---------------- final FC: out[b,o] = h1 . Wfc[o] + bfc[o] ----------------
__global__ void fc_k(const float* __restrict__ h1f, const float* __restrict__ Wfc,
                     const float* __restrict__ bfc, float* __restrict__ out) {
    int idx = blockIdx.x * 256 + threadIdx.x;
    if (idx >= 64 * 1000) return;
    int o = idx % 1000;
    int b = idx / 1000;
    const float4* hr = (const float4*)(h1f + b * H_);
    const float4* wr = (const float4*)(Wfc + (size_t)o * H_);
    float s = 0.f;
    #pragma unroll 4
    for (int k = 0; k < 256; ++k) {
        float4 a = hr[k];
        float4 w = wr[k];
        s += a.x * w.x + a.y * w.y + a.z * w.z + a.w * w.w;
    }
    out[idx] = s + bfc[o];
}

extern "C" void kernel_launch(void* const* d_in, const int* in_sizes, int n_in,
                              void* d_out, int out_size, void* d_ws, size_t ws_size,
                              hipStream_t stream) {
    const float* x    = (const float*)d_in[0];
    const float* h0in = (const float*)d_in[1];
    const float* c0in = (const float*)d_in[2];
    const float* Wih0 = (const float*)d_in[3];
    const float* Whh0 = (const float*)d_in[4];
    const float* bih0 = (const float*)d_in[5];
    const float* bhh0 = (const float*)d_in[6];
    const float* Wih1 = (const float*)d_in[7];
    const float* Whh1 = (const float*)d_in[8];
    const float* bih1 = (const float*)d_in[9];
    const float* bhh1 = (const float*)d_in[10];
    const float* Wfc  = (const float*)d_in[11];
    const float* bfc  = (const float*)d_in[12];
    float* out = (float*)d_out;

    char* ws = (char*)d_ws;
    size_t off = 0;
    auto alloc = [&](size_t bytes) {
        void* p = ws + off;
        off += (bytes + 255) & ~(size_t)255;
        return p;
    };
    u16* W0c   = (u16*)alloc((size_t)4096 * 1536 * 2);
    u16* W1c   = (u16*)alloc((size_t)4096 * 2048 * 2);
    float* bias0 = (float*)alloc(4096 * 4);
    float* bias1 = (float*)alloc(4096 * 4);
    u16* h0A   = (u16*)alloc(B_ * H_ * 2);
    u16* h0B   = (u16*)alloc(B_ * H_ * 2);
    u16* h1A   = (u16*)alloc(B_ * H_ * 2);
    u16* h1B   = (u16*)alloc(B_ * H_ * 2);
    float* h1f = (float*)alloc(B_ * H_ * 4);
    int* bar   = (int*)alloc(32768);   // 256 flags, 128B apart

    prep_w<<<786432 / 256, 256, 0, stream>>>(Wih0, Whh0, W0c, 512, 1536, 786432);
    prep_w<<<1048576 / 256, 256, 0, stream>>>(Wih1, Whh1, W1c, 1024, 2048, 1048576);
    prep_misc2<<<(8192 + 2 * B_ * H_ + 255) / 256, 256, 0, stream>>>(
        h0in, bih0, bhh0, bih1, bhh1, bias0, bias1, h0A, h0B, h1A, h1B, bar);

    void* args[] = {(void*)&x, (void*)&W0c, (void*)&W1c, (void*)&bias0, (void*)&bias1,
                    (void*)&c0in, (void*)&h0A, (void*)&h0B, (void*)&h1A, (void*)&h1B,
                    (void*)&h1f, (void*)&bar};
    hipLaunchCooperativeKernel((void*)lstm_persist, dim3(256), dim3(512), args, 0, stream);

    fc_k<<<(64000 + 255) / 256, 256, 0, stream>>>(h1f, Wfc, bfc, out);
}